// Round 4
// baseline (333.038 us; speedup 1.0000x reference)
//
#include <hip/hip_runtime.h>

typedef unsigned short u16;
typedef unsigned int u32;

#define S 2048
#define HID 2048
#define NH 16
#define NKV 4
#define D 128
#define QKVP 3072  // QKV buffer pitch (Q|K|V concat per row)
// 1/sqrt(128) * log2(e): scores come out of QK^T already in log2 domain
#define QSCALE (0.08838834764831845f * 1.4426950408889634f)
#define NEG_INF -3.0e38f

typedef __attribute__((ext_vector_type(8))) short short8;  // 8 bf16 = 4 VGPRs
typedef __attribute__((ext_vector_type(4))) float f32x4;

__device__ __forceinline__ float bf2f(u16 u) {
  union { u32 i; float f; } c; c.i = ((u32)u) << 16; return c.f;
}
__device__ __forceinline__ u16 f2bf(float f) {
  union { float f; u32 i; } c; c.f = f;
  u32 x = c.i;
  u32 r = x + 0x7fffu + ((x >> 16) & 1u);  // RNE
  return (u16)(r >> 16);
}

#if __has_builtin(__builtin_amdgcn_exp2f)
__device__ __forceinline__ float exp2_hw(float x) { return __builtin_amdgcn_exp2f(x); }
#else
__device__ __forceinline__ float exp2_hw(float x) { return exp2f(x); }
#endif

// packed f32x2 -> bf16x2 (RNE), single VOP3
__device__ __forceinline__ u32 cvt_pk_bf16(float a, float b) {
  u32 r;
  asm("v_cvt_pk_bf16_f32 %0, %1, %2" : "=v"(r) : "v"(a), "v"(b));
  return r;
}

__device__ __forceinline__ void gload16(const u16* g, u16* l) {
  __builtin_amdgcn_global_load_lds(
      (const __attribute__((address_space(1))) u32*)g,
      (__attribute__((address_space(3))) u32*)l, 16, 0, 0);
}

// ---------------- f32 -> bf16 elementwise convert ---------------------------
__global__ __launch_bounds__(256) void k_cvt(const float* __restrict__ src,
                                             u16* __restrict__ dst) {
  int i = (blockIdx.x * 256 + threadIdx.x) * 8;
  float4 v0 = *(const float4*)(src + i);
  float4 v1 = *(const float4*)(src + i + 4);
  ushort4 w0, w1;
  w0.x = f2bf(v0.x); w0.y = f2bf(v0.y); w0.z = f2bf(v0.z); w0.w = f2bf(v0.w);
  w1.x = f2bf(v1.x); w1.y = f2bf(v1.y); w1.z = f2bf(v1.z); w1.w = f2bf(v1.w);
  *(ushort4*)(dst + i) = w0;
  *(ushort4*)(dst + i + 4) = w1;
}

// ------- transpose + convert body: src[K][N] f32 -> dst[N][K] bf16 ----------
__device__ __forceinline__ void transpose_body(const float* __restrict__ src,
                                               u16* __restrict__ dst,
                                               int N, int K, int nt, int kt,
                                               int t) {
  __shared__ float T[64][65];
#pragma unroll
  for (int it = 0; it < 4; ++it) {
    int r = it * 16 + (t >> 4), c = (t & 15) * 4;
    float4 v = *(const float4*)(src + (size_t)(kt + r) * N + nt + c);
    T[r][c] = v.x; T[r][c + 1] = v.y; T[r][c + 2] = v.z; T[r][c + 3] = v.w;
  }
  __syncthreads();
#pragma unroll
  for (int it = 0; it < 2; ++it) {
    int n = it * 32 + (t >> 3), k8 = (t & 7) * 8;
    ushort4 w0, w1;
    w0.x = f2bf(T[k8 + 0][n]); w0.y = f2bf(T[k8 + 1][n]);
    w0.z = f2bf(T[k8 + 2][n]); w0.w = f2bf(T[k8 + 3][n]);
    w1.x = f2bf(T[k8 + 4][n]); w1.y = f2bf(T[k8 + 5][n]);
    w1.z = f2bf(T[k8 + 6][n]); w1.w = f2bf(T[k8 + 7][n]);
    *(ushort4*)(dst + (size_t)(nt + n) * K + kt + k8) = w0;
    *(ushort4*)(dst + (size_t)(nt + n) * K + kt + k8 + 4) = w1;
  }
}

__global__ __launch_bounds__(256) void k_transpose(const float* __restrict__ src,
                                                   u16* __restrict__ dst,
                                                   int N, int K) {
  transpose_body(src, dst, N, K, blockIdx.x * 64, blockIdx.y * 64, threadIdx.x);
}

// merged Wq|Wk|Wv transpose (one launch)
__global__ __launch_bounds__(256) void k_transpose_qkv(const float* __restrict__ Wq,
                                                       const float* __restrict__ Wk,
                                                       const float* __restrict__ Wv,
                                                       u16* __restrict__ WT) {
  const int bx = blockIdx.x;
  const float* src; u16* dst; int N, nt;
  if (bx < 32)      { src = Wq; dst = WT;                    N = 2048; nt = bx * 64; }
  else if (bx < 40) { src = Wk; dst = WT + 2048ull * 2048;   N = 512;  nt = (bx - 32) * 64; }
  else              { src = Wv; dst = WT + 2560ull * 2048;   N = 512;  nt = (bx - 40) * 64; }
  transpose_body(src, dst, N, 2048, nt, blockIdx.y * 64, threadIdx.x);
}

// ------- V transpose: QKV V-section [s][2560+gd] bf16 -> Vt[gd][s] bf16 -----
__global__ __launch_bounds__(256) void k_vt(const u16* __restrict__ QKV,
                                            u16* __restrict__ Vt) {
  __shared__ u16 T[64][66];
  const int t = threadIdx.x;
  const int s0 = blockIdx.x * 64, d0 = blockIdx.y * 64;
#pragma unroll
  for (int it = 0; it < 4; ++it) {
    int r = it * 16 + (t >> 4), c = (t & 15) * 4;
    ushort4 v = *(const ushort4*)(QKV + (size_t)(s0 + r) * QKVP + 2560 + d0 + c);
    T[r][c] = v.x; T[r][c + 1] = v.y; T[r][c + 2] = v.z; T[r][c + 3] = v.w;
  }
  __syncthreads();
#pragma unroll
  for (int it = 0; it < 4; ++it) {
    int dd = it * 16 + (t >> 4), sc = (t & 15) * 4;
    ushort4 w;
    w.x = T[sc + 0][dd]; w.y = T[sc + 1][dd];
    w.z = T[sc + 2][dd]; w.w = T[sc + 3][dd];
    *(ushort4*)(Vt + (size_t)(d0 + dd) * S + s0 + sc) = w;
  }
}

// ---------------- MFMA GEMM, 2-phase prefetch pipeline (R1-proven) ----------
__global__ __launch_bounds__(256) void k_gemm_mfma(const u16* __restrict__ A,
                                                   const u16* __restrict__ BT,
                                                   void* __restrict__ Cout,
                                                   int N, int K, int out_bf16) {
  __shared__ __align__(16) u16 As[2][128 * 32];
  __shared__ __align__(16) u16 Bs[2][128 * 32];
  const int t = threadIdx.x, w = t >> 6, lane = t & 63;
  const int l15 = lane & 15, quad = lane >> 4;
  const int m0 = blockIdx.y * 128, n0 = blockIdx.x * 128;
  const int wr = w >> 1, wc = w & 1;

  const int sr = w * 16 + (lane >> 2);
  const int sk8 = (lane & 3) * 8;
  const u16* Ag0 = A + (size_t)(m0 + sr) * K + sk8;
  const u16* Ag1 = A + (size_t)(m0 + 64 + sr) * K + sk8;
  const u16* Bg0 = BT + (size_t)(n0 + sr) * K + sk8;
  const u16* Bg1 = BT + (size_t)(n0 + 64 + sr) * K + sk8;

  f32x4 acc[4][4];
#pragma unroll
  for (int i = 0; i < 4; ++i)
#pragma unroll
    for (int j = 0; j < 4; ++j) acc[i][j] = (f32x4){0.f, 0.f, 0.f, 0.f};

  auto STAGE = [&](int k0, int b) {
    gload16(Ag0 + k0, &As[b][w * 512]);
    gload16(Ag1 + k0, &As[b][2048 + w * 512]);
    gload16(Bg0 + k0, &Bs[b][w * 512]);
    gload16(Bg1 + k0, &Bs[b][2048 + w * 512]);
  };

  STAGE(0, 0);
  __syncthreads();  // buf0 ready
  int cur = 0;
  for (int k0 = 0; k0 < K; k0 += 32) {
    if (k0 + 32 < K) STAGE(k0 + 32, cur ^ 1);  // issue next tile early

    short8 af[4], bf[4];
#pragma unroll
    for (int i = 0; i < 4; ++i)
      af[i] = *(const short8*)&As[cur][(wr * 64 + i * 16 + l15) * 32 + quad * 8];
#pragma unroll
    for (int j = 0; j < 4; ++j)
      bf[j] = *(const short8*)&Bs[cur][(wc * 64 + j * 16 + l15) * 32 + quad * 8];
#pragma unroll
    for (int i = 0; i < 4; ++i)
#pragma unroll
      for (int j = 0; j < 4; ++j)
        acc[i][j] = __builtin_amdgcn_mfma_f32_16x16x32_bf16(af[i], bf[j], acc[i][j], 0, 0, 0);

    __syncthreads();  // drains prefetch + all waves done reading cur
    cur ^= 1;
  }

  if (out_bf16) {
    u16* C = (u16*)Cout;
#pragma unroll
    for (int i = 0; i < 4; ++i)
#pragma unroll
      for (int j = 0; j < 4; ++j) {
        int col = n0 + wc * 64 + j * 16 + l15;
#pragma unroll
        for (int r = 0; r < 4; ++r)
          C[(size_t)(m0 + wr * 64 + i * 16 + quad * 4 + r) * N + col] = f2bf(acc[i][j][r]);
      }
  } else {
    float* C = (float*)Cout;
#pragma unroll
    for (int i = 0; i < 4; ++i)
#pragma unroll
      for (int j = 0; j < 4; ++j) {
        int col = n0 + wc * 64 + j * 16 + l15;
#pragma unroll
        for (int r = 0; r < 4; ++r)
          C[(size_t)(m0 + wr * 64 + i * 16 + quad * 4 + r) * N + col] = acc[i][j][r];
      }
  }
}

// ------------- per-(s,head) RMSNorm + RoPE, Q and K in one launch (R1) ------
__global__ __launch_bounds__(128) void k_norm_rope(u16* __restrict__ QKV,
                                                   const float* __restrict__ qsc,
                                                   const float* __restrict__ ksc,
                                                   const float* __restrict__ cosp,
                                                   const float* __restrict__ sinp) {
  const int s = blockIdx.x, hh = blockIdx.y, d = threadIdx.x;
  u16* row; const float* sc; float scale;
  if (hh < NH) { row = QKV + (size_t)s * QKVP + hh * D;            sc = qsc; scale = QSCALE; }
  else         { row = QKV + (size_t)s * QKVP + 2048 + (hh - NH) * D; sc = ksc; scale = 1.0f; }
  float x = bf2f(row[d]);
  float v = x * x;
#pragma unroll
  for (int o = 32; o; o >>= 1) v += __shfl_xor(v, o, 64);
  __shared__ float red[2];
  if ((d & 63) == 0) red[d >> 6] = v;
  __syncthreads();
  float var = (red[0] + red[1]) * (1.0f / 128.0f);
  float rinv = rsqrtf(var + 1e-6f) * scale;
  float xn = x * rinv * sc[d];
  __shared__ float sh[D];
  sh[d] = xn;
  __syncthreads();
  float rot = (d < 64) ? -sh[d + 64] : sh[d - 64];
  row[d] = f2bf(xn * cosp[s * D + d] + rot * sinp[s * D + d]);
}

// ---------------- flash attention: R1 skeleton + V-direct -------------------
// Block: 256 thr (4 waves) = 64-row q-tile of one head.
// K: global_load_lds double-buffer, source-chunk-swizzled (R1-proven);
//    prefetch for jt+1 issued right after the per-tile barrier.
// V: fragments read DIRECTLY from global Vt (2 MB, L2-resident) at the exact
//    addresses R1's VLOAD used -- no Vlds, no V barriers.
// Softmax: exp2-domain (R1-proven) + HARDENED defer-rescale: jt==0 always
//    rescales with alpha forced to 0.f (no exp2(+-3e38) edge); jt>0 defers
//    while all lanes' growth <= 8 (P bounded by 2^8, bf16-safe).
#define KP 128   // K LDS row pitch (u16), unpadded (DMA requirement)
#define PTP 72   // P pitch (u16): b64-write / b128-read aligned

__global__ __launch_bounds__(256) void k_flash(const u16* __restrict__ QKV,
                                               const u16* __restrict__ Vt,
                                               u16* __restrict__ O) {
  const int h = blockIdx.y, g = h >> 2;
  const int qt = (h < 8) ? (31 - (int)blockIdx.x) : (int)blockIdx.x;
  const int t = threadIdx.x;
  const int w = t >> 6, lane = t & 63, l15 = lane & 15, quad = lane >> 4;

  __shared__ __align__(16) u16 Klds[2][64 * KP];
  __shared__ __align__(16) u16 Pt[4][16 * PTP];    // [qcol][key] per wave

  const int qbase = qt * 64 + w * 16;
  const int qrow = qbase + l15;

  short8 qf[4];
  {
    const u16* qp = QKV + (size_t)qrow * QKVP + h * D + quad * 8;
#pragma unroll
    for (int c = 0; c < 4; ++c) qf[c] = *(const short8*)(qp + c * 32);
  }

  float m = NEG_INF, l = 0.f;
  f32x4 oacc[8];
#pragma unroll
  for (int nc = 0; nc < 8; ++nc) oacc[nc] = (f32x4){0.f, 0.f, 0.f, 0.f};

  const int nt = qt + 1;

  auto KLOAD = [&](int j0, int b) {  // DMA 4 rows per wave per issue
#pragma unroll
    for (int it = 0; it < 4; ++it) {
      int rl = w * 16 + it * 4 + quad;                 // tile-local key row
      int gchunk = (lane & 15) ^ (rl & 7);             // source swizzle
      const u16* gp = QKV + (size_t)(j0 + rl) * QKVP + 2048 + g * D + gchunk * 8;
      gload16(gp, &Klds[b][(w * 16 + it * 4) * KP]);
    }
  };

  KLOAD(0, 0);
  for (int jt = 0; jt < nt; ++jt) {
    const int b = jt & 1;
    __syncthreads();  // K(jt) DMA drained (vmcnt0+lgkmcnt0+barrier)
    if (jt + 1 < nt) KLOAD((jt + 1) * 64, b ^ 1);

    const int j0 = jt * 64;
    const u16* vbase = Vt + (size_t)g * D * S + j0;

    // V fragments kc=0 (keys j0 + quad*8..+7): same elements R1 staged via
    // Vlds; issued early so L2 latency hides under QK^T.
    short8 vf0[8];
#pragma unroll
    for (int nc = 0; nc < 8; ++nc)
      vf0[nc] = *(const short8*)(vbase + (size_t)(nc * 16 + l15) * S + quad * 8);

    // ---- S^T = K x Q^T : row = key (quad*4+r +16sub), col = q-row (l15) ----
    f32x4 sa[4];
#pragma unroll
    for (int sub = 0; sub < 4; ++sub) {
      f32x4 acc = {0.f, 0.f, 0.f, 0.f};
#pragma unroll
      for (int c = 0; c < 4; ++c) {
        int ch = (c * 4 + quad) ^ (l15 & 7);  // undo source swizzle
        short8 kf = *(const short8*)&Klds[b][(sub * 16 + l15) * KP + ch * 8];
        acc = __builtin_amdgcn_mfma_f32_16x16x32_bf16(kf, qf[c], acc, 0, 0, 0);
      }
      sa[sub] = acc;
    }

    // V fragments kc=1 (keys j0+32+quad*8..+7)
    short8 vf1[8];
#pragma unroll
    for (int nc = 0; nc < 8; ++nc)
      vf1[nc] = *(const short8*)(vbase + (size_t)(nc * 16 + l15) * S + 32 + quad * 8);

    if (jt == nt - 1) {  // causal mask, diagonal tile only
#pragma unroll
      for (int sub = 0; sub < 4; ++sub) {
        int keyb = j0 + sub * 16 + quad * 4;
#pragma unroll
        for (int r = 0; r < 4; ++r)
          if (keyb + r > qrow) sa[sub][r] = NEG_INF;
      }
    }

    // ---- online softmax (exp2 domain, hardened defer-rescale THR=8) -------
    float tmax = sa[0][0];
#pragma unroll
    for (int sub = 0; sub < 4; ++sub)
#pragma unroll
      for (int r = 0; r < 4; ++r) tmax = fmaxf(tmax, sa[sub][r]);
    tmax = fmaxf(tmax, __shfl_xor(tmax, 16, 64));
    tmax = fmaxf(tmax, __shfl_xor(tmax, 32, 64));
    if (jt == 0 || !__all(tmax - m <= 8.f)) {
      float mn = (jt == 0) ? tmax : fmaxf(m, tmax);
      float alpha = (jt == 0) ? 0.f : exp2_hw(m - mn);
      m = mn;
      l *= alpha;
#pragma unroll
      for (int nc = 0; nc < 8; ++nc) {
        oacc[nc][0] *= alpha; oacc[nc][1] *= alpha;
        oacc[nc][2] *= alpha; oacc[nc][3] *= alpha;
      }
    }
    float rs = 0.f;
#pragma unroll
    for (int sub = 0; sub < 4; ++sub) {
      float p0 = exp2_hw(sa[sub][0] - m);
      float p1 = exp2_hw(sa[sub][1] - m);
      float p2 = exp2_hw(sa[sub][2] - m);
      float p3 = exp2_hw(sa[sub][3] - m);
      rs += (p0 + p1) + (p2 + p3);
      u32 lo = cvt_pk_bf16(p0, p1);
      u32 hi = cvt_pk_bf16(p2, p3);
      *(uint2*)&Pt[w][l15 * PTP + sub * 16 + quad * 4] = make_uint2(lo, hi);
    }
    rs += __shfl_xor(rs, 16, 64);
    rs += __shfl_xor(rs, 32, 64);
    l += rs;

    // ---- O^T += V^T x P^T (V fragments already in regs) -------------------
    {
      short8 pf0 = *(const short8*)&Pt[w][l15 * PTP + quad * 8];
      short8 pf1 = *(const short8*)&Pt[w][l15 * PTP + 32 + quad * 8];
#pragma unroll
      for (int nc = 0; nc < 8; ++nc)
        oacc[nc] = __builtin_amdgcn_mfma_f32_16x16x32_bf16(vf0[nc], pf0, oacc[nc], 0, 0, 0);
#pragma unroll
      for (int nc = 0; nc < 8; ++nc)
        oacc[nc] = __builtin_amdgcn_mfma_f32_16x16x32_bf16(vf1[nc], pf1, oacc[nc], 0, 0, 0);
    }
  }

  // ---- epilogue: O[q][d] = O^T / l ----
  float inv = 1.0f / l;
  u16* orow = O + (size_t)qrow * HID + h * D;
#pragma unroll
  for (int nc = 0; nc < 8; ++nc) {
    ushort4 wv;
    wv.x = f2bf(oacc[nc][0] * inv); wv.y = f2bf(oacc[nc][1] * inv);
    wv.z = f2bf(oacc[nc][2] * inv); wv.w = f2bf(oacc[nc][3] * inv);
    *(ushort4*)(orow + nc * 16 + quad * 4) = wv;
  }
}

// ---------------- final RMSNorm over HIDDEN=2048 ----------------------------
__device__ __forceinline__ float blockSum256(float v, float* red, int t) {
#pragma unroll
  for (int o = 32; o; o >>= 1) v += __shfl_xor(v, o, 64);
  if ((t & 63) == 0) red[t >> 6] = v;
  __syncthreads();
  v = red[0] + red[1] + red[2] + red[3];
  __syncthreads();
  return v;
}

__global__ __launch_bounds__(256) void k_fnorm(const float* __restrict__ X,
                                               const float* __restrict__ sc,
                                               float* __restrict__ out) {
  const int s = blockIdx.x, t = threadIdx.x;
  const float* row = X + (size_t)s * HID;
  float4 r0 = *(const float4*)(row + t * 8);
  float4 r1 = *(const float4*)(row + t * 8 + 4);
  float x[8] = {r0.x, r0.y, r0.z, r0.w, r1.x, r1.y, r1.z, r1.w};
  float ss = 0.f;
#pragma unroll
  for (int ii = 0; ii < 8; ++ii) ss += x[ii] * x[ii];
  __shared__ float red[4];
  float tot = blockSum256(ss, red, t);
  float rinv = rsqrtf(tot * (1.0f / 2048.0f) + 1e-6f);
  float4 s0 = *(const float4*)(sc + t * 8);
  float4 s1 = *(const float4*)(sc + t * 8 + 4);
  float4 w0 = make_float4(x[0] * rinv * s0.x, x[1] * rinv * s0.y,
                          x[2] * rinv * s0.z, x[3] * rinv * s0.w);
  float4 w1 = make_float4(x[4] * rinv * s1.x, x[5] * rinv * s1.y,
                          x[6] * rinv * s1.z, x[7] * rinv * s1.w);
  *(float4*)(out + (size_t)s * HID + t * 8) = w0;
  *(float4*)(out + (size_t)s * HID + t * 8 + 4) = w1;
}

extern "C" void kernel_launch(void* const* d_in, const int* in_sizes, int n_in,
                              void* d_out, int out_size, void* d_ws, size_t ws_size,
                              hipStream_t stream) {
  const float* hidden = (const float*)d_in[0];
  const float* cosp   = (const float*)d_in[1];
  const float* sinp   = (const float*)d_in[2];
  const float* Wq     = (const float*)d_in[3];
  const float* Wk     = (const float*)d_in[4];
  const float* Wv     = (const float*)d_in[5];
  const float* Wo     = (const float*)d_in[6];
  const float* qsc    = (const float*)d_in[7];
  const float* ksc    = (const float*)d_in[8];
  const float* lsc    = (const float*)d_in[9];
  float* out = (float*)d_out;

  char* ws = (char*)d_ws;
  u16*   Hb  = (u16*)(ws);                   // [S][HID] bf16, 8 MiB
  u16*   WoT = (u16*)(ws);                   // overlays Hb (after QKV GEMM)
  u16*   WT  = (u16*)(ws + (8ull << 20));    // [3072][2048] bf16, 12 MiB
  u16*   An  = (u16*)(ws + (8ull << 20));    // overlays WT (after QKV GEMM)
  u16*   QKV = (u16*)(ws + (20ull << 20));   // [S][3072] bf16, 12 MiB
  float* Ob  = (float*)(ws + (20ull << 20)); // overlays QKV (after flash)
  u16*   Vtb = (u16*)(ws + (32ull << 20));   // [512][2048] bf16, 2 MiB

  k_cvt<<<S * HID / (256 * 8), 256, 0, stream>>>(hidden, Hb);
  k_transpose_qkv<<<dim3(48, 32), 256, 0, stream>>>(Wq, Wk, Wv, WT);
  k_gemm_mfma<<<dim3(24, 16), 256, 0, stream>>>(Hb, WT, QKV, QKVP, 2048, 1);
  k_transpose<<<dim3(32, 32), 256, 0, stream>>>(Wo, WoT, 2048, 2048);  // Hb dead
  k_norm_rope<<<dim3(S, NH + NKV), 128, 0, stream>>>(QKV, qsc, ksc, cosp, sinp);
  k_vt<<<dim3(32, 8), 256, 0, stream>>>(QKV, Vtb);
  k_flash<<<dim3(32, NH), 256, 0, stream>>>(QKV, Vtb, An);
  k_gemm_mfma<<<dim3(16, 16), 256, 0, stream>>>(An, WoT, Ob, 2048, 2048, 0);
  k_fnorm<<<S, 256, 0, stream>>>(Ob, lsc, out);
}

// Round 5
// 307.537 us; speedup vs baseline: 1.0829x; 1.0829x over previous
//
#include <hip/hip_runtime.h>

typedef unsigned short u16;
typedef unsigned int u32;

#define S 2048
#define HID 2048
#define NH 16
#define NKV 4
#define D 128
#define QKVP 3072  // QKV buffer pitch (Q|K|V concat per row)
// 1/sqrt(128) * log2(e): scores come out of QK^T already in log2 domain
#define QSCALE (0.08838834764831845f * 1.4426950408889634f)
#define NEG_INF -3.0e38f

typedef __attribute__((ext_vector_type(8))) short short8;  // 8 bf16 = 4 VGPRs
typedef __attribute__((ext_vector_type(4))) float f32x4;

__device__ __forceinline__ float bf2f(u16 u) {
  union { u32 i; float f; } c; c.i = ((u32)u) << 16; return c.f;
}
__device__ __forceinline__ u16 f2bf(float f) {
  union { float f; u32 i; } c; c.f = f;
  u32 x = c.i;
  u32 r = x + 0x7fffu + ((x >> 16) & 1u);  // RNE
  return (u16)(r >> 16);
}

#if __has_builtin(__builtin_amdgcn_exp2f)
__device__ __forceinline__ float exp2_hw(float x) { return __builtin_amdgcn_exp2f(x); }
#else
__device__ __forceinline__ float exp2_hw(float x) { return exp2f(x); }
#endif

// packed f32x2 -> bf16x2 (RNE), single VOP3
__device__ __forceinline__ u32 cvt_pk_bf16(float a, float b) {
  u32 r;
  asm("v_cvt_pk_bf16_f32 %0, %1, %2" : "=v"(r) : "v"(a), "v"(b));
  return r;
}

__device__ __forceinline__ void gload16(const u16* g, u16* l) {
  __builtin_amdgcn_global_load_lds(
      (const __attribute__((address_space(1))) u32*)g,
      (__attribute__((address_space(3))) u32*)l, 16, 0, 0);
}

// ---------------- f32 -> bf16 elementwise convert ---------------------------
__global__ __launch_bounds__(256) void k_cvt(const float* __restrict__ src,
                                             u16* __restrict__ dst) {
  int i = (blockIdx.x * 256 + threadIdx.x) * 8;
  float4 v0 = *(const float4*)(src + i);
  float4 v1 = *(const float4*)(src + i + 4);
  ushort4 w0, w1;
  w0.x = f2bf(v0.x); w0.y = f2bf(v0.y); w0.z = f2bf(v0.z); w0.w = f2bf(v0.w);
  w1.x = f2bf(v1.x); w1.y = f2bf(v1.y); w1.z = f2bf(v1.z); w1.w = f2bf(v1.w);
  *(ushort4*)(dst + i) = w0;
  *(ushort4*)(dst + i + 4) = w1;
}

// ------- transpose + convert body: src[K][N] f32 -> dst[N][K] bf16 ----------
__device__ __forceinline__ void transpose_body(const float* __restrict__ src,
                                               u16* __restrict__ dst,
                                               int N, int K, int nt, int kt,
                                               int t) {
  __shared__ float T[64][65];
#pragma unroll
  for (int it = 0; it < 4; ++it) {
    int r = it * 16 + (t >> 4), c = (t & 15) * 4;
    float4 v = *(const float4*)(src + (size_t)(kt + r) * N + nt + c);
    T[r][c] = v.x; T[r][c + 1] = v.y; T[r][c + 2] = v.z; T[r][c + 3] = v.w;
  }
  __syncthreads();
#pragma unroll
  for (int it = 0; it < 2; ++it) {
    int n = it * 32 + (t >> 3), k8 = (t & 7) * 8;
    ushort4 w0, w1;
    w0.x = f2bf(T[k8 + 0][n]); w0.y = f2bf(T[k8 + 1][n]);
    w0.z = f2bf(T[k8 + 2][n]); w0.w = f2bf(T[k8 + 3][n]);
    w1.x = f2bf(T[k8 + 4][n]); w1.y = f2bf(T[k8 + 5][n]);
    w1.z = f2bf(T[k8 + 6][n]); w1.w = f2bf(T[k8 + 7][n]);
    *(ushort4*)(dst + (size_t)(nt + n) * K + kt + k8) = w0;
    *(ushort4*)(dst + (size_t)(nt + n) * K + kt + k8 + 4) = w1;
  }
}

__global__ __launch_bounds__(256) void k_transpose(const float* __restrict__ src,
                                                   u16* __restrict__ dst,
                                                   int N, int K) {
  transpose_body(src, dst, N, K, blockIdx.x * 64, blockIdx.y * 64, threadIdx.x);
}

// merged Wq|Wk|Wv transpose (one launch)
__global__ __launch_bounds__(256) void k_transpose_qkv(const float* __restrict__ Wq,
                                                       const float* __restrict__ Wk,
                                                       const float* __restrict__ Wv,
                                                       u16* __restrict__ WT) {
  const int bx = blockIdx.x;
  const float* src; u16* dst; int N, nt;
  if (bx < 32)      { src = Wq; dst = WT;                    N = 2048; nt = bx * 64; }
  else if (bx < 40) { src = Wk; dst = WT + 2048ull * 2048;   N = 512;  nt = (bx - 32) * 64; }
  else              { src = Wv; dst = WT + 2560ull * 2048;   N = 512;  nt = (bx - 40) * 64; }
  transpose_body(src, dst, N, 2048, nt, blockIdx.y * 64, threadIdx.x);
}

// ------- V transpose: QKV V-section [s][2560+gd] bf16 -> Vt[gd][s] bf16 -----
__global__ __launch_bounds__(256) void k_vt(const u16* __restrict__ QKV,
                                            u16* __restrict__ Vt) {
  __shared__ u16 T[64][66];
  const int t = threadIdx.x;
  const int s0 = blockIdx.x * 64, d0 = blockIdx.y * 64;
#pragma unroll
  for (int it = 0; it < 4; ++it) {
    int r = it * 16 + (t >> 4), c = (t & 15) * 4;
    ushort4 v = *(const ushort4*)(QKV + (size_t)(s0 + r) * QKVP + 2560 + d0 + c);
    T[r][c] = v.x; T[r][c + 1] = v.y; T[r][c + 2] = v.z; T[r][c + 3] = v.w;
  }
  __syncthreads();
#pragma unroll
  for (int it = 0; it < 4; ++it) {
    int dd = it * 16 + (t >> 4), sc = (t & 15) * 4;
    ushort4 w;
    w.x = T[sc + 0][dd]; w.y = T[sc + 1][dd];
    w.z = T[sc + 2][dd]; w.w = T[sc + 3][dd];
    *(ushort4*)(Vt + (size_t)(d0 + dd) * S + s0 + sc) = w;
  }
}

// ---------------- MFMA GEMM: BK=64, 2-phase prefetch, XOR-swizzled LDS ------
// BK=64 gives 128B LDS row stride -> XOR chunk swizzle makes frag reads
// conflict-free (BK=32's 64B stride is stuck at 8-way); 32 MFMAs per barrier
// (was 16) halves the per-step barrier-drain tax.
// LDS layout: tile[row][chunk c] = src[row][c ^ (row&7)] (chunks of 8 u16).
// Staged via per-lane pre-swizzled global source (rule: swizzle both sides).
__global__ __launch_bounds__(256) void k_gemm_mfma(const u16* __restrict__ A,
                                                   const u16* __restrict__ BT,
                                                   void* __restrict__ Cout,
                                                   int N, int K, int out_bf16) {
  __shared__ __align__(16) u16 As[2][128 * 64];
  __shared__ __align__(16) u16 Bs[2][128 * 64];
  const int t = threadIdx.x, w = t >> 6, lane = t & 63;
  const int l15 = lane & 15, quad = lane >> 4;
  const int m0 = blockIdx.y * 128, n0 = blockIdx.x * 128;
  const int wr = w >> 1, wc = w & 1;

  // staging: per issue, wave covers 8 rows (8 lanes/row, 16B each).
  const int srow = lane >> 3;                       // 0..7 within issue
  const int schunk = (lane & 7) ^ srow;             // pre-swizzled source chunk
  const u16* Agb = A + (size_t)(m0 + w * 8 + srow) * K + schunk * 8;
  const u16* Bgb = BT + (size_t)(n0 + w * 8 + srow) * K + schunk * 8;

  f32x4 acc[4][4];
#pragma unroll
  for (int i = 0; i < 4; ++i)
#pragma unroll
    for (int j = 0; j < 4; ++j) acc[i][j] = (f32x4){0.f, 0.f, 0.f, 0.f};

  auto STAGE = [&](int k0, int b) {
#pragma unroll
    for (int it = 0; it < 4; ++it) {
      gload16(Agb + (size_t)it * 32 * K + k0, &As[b][(w * 8 + it * 32) * 64]);
      gload16(Bgb + (size_t)it * 32 * K + k0, &Bs[b][(w * 8 + it * 32) * 64]);
    }
  };

  STAGE(0, 0);
  __syncthreads();  // buf0 ready
  int cur = 0;
  for (int k0 = 0; k0 < K; k0 += 64) {
    if (k0 + 64 < K) STAGE(k0 + 64, cur ^ 1);  // issue next tile early

    short8 af[4][2], bf[4][2];
#pragma unroll
    for (int i = 0; i < 4; ++i)
#pragma unroll
      for (int k2 = 0; k2 < 2; ++k2) {
        int ch = (k2 * 4 + quad) ^ (l15 & 7);
        af[i][k2] = *(const short8*)&As[cur][(wr * 64 + i * 16 + l15) * 64 + ch * 8];
        bf[i][k2] = *(const short8*)&Bs[cur][(wc * 64 + i * 16 + l15) * 64 + ch * 8];
      }
#pragma unroll
    for (int k2 = 0; k2 < 2; ++k2)
#pragma unroll
      for (int i = 0; i < 4; ++i)
#pragma unroll
        for (int j = 0; j < 4; ++j)
          acc[i][j] = __builtin_amdgcn_mfma_f32_16x16x32_bf16(af[i][k2], bf[j][k2], acc[i][j], 0, 0, 0);

    __syncthreads();  // drains prefetch + all waves done reading cur
    cur ^= 1;
  }

  if (out_bf16) {
    u16* C = (u16*)Cout;
#pragma unroll
    for (int i = 0; i < 4; ++i)
#pragma unroll
      for (int j = 0; j < 4; ++j) {
        int col = n0 + wc * 64 + j * 16 + l15;
#pragma unroll
        for (int r = 0; r < 4; ++r)
          C[(size_t)(m0 + wr * 64 + i * 16 + quad * 4 + r) * N + col] = f2bf(acc[i][j][r]);
      }
  } else {
    float* C = (float*)Cout;
#pragma unroll
    for (int i = 0; i < 4; ++i)
#pragma unroll
      for (int j = 0; j < 4; ++j) {
        int col = n0 + wc * 64 + j * 16 + l15;
#pragma unroll
        for (int r = 0; r < 4; ++r)
          C[(size_t)(m0 + wr * 64 + i * 16 + quad * 4 + r) * N + col] = acc[i][j][r];
      }
  }
}

// ------------- per-(s,head) RMSNorm + RoPE, Q and K in one launch (R1) ------
__global__ __launch_bounds__(128) void k_norm_rope(u16* __restrict__ QKV,
                                                   const float* __restrict__ qsc,
                                                   const float* __restrict__ ksc,
                                                   const float* __restrict__ cosp,
                                                   const float* __restrict__ sinp) {
  const int s = blockIdx.x, hh = blockIdx.y, d = threadIdx.x;
  u16* row; const float* sc; float scale;
  if (hh < NH) { row = QKV + (size_t)s * QKVP + hh * D;            sc = qsc; scale = QSCALE; }
  else         { row = QKV + (size_t)s * QKVP + 2048 + (hh - NH) * D; sc = ksc; scale = 1.0f; }
  float x = bf2f(row[d]);
  float v = x * x;
#pragma unroll
  for (int o = 32; o; o >>= 1) v += __shfl_xor(v, o, 64);
  __shared__ float red[2];
  if ((d & 63) == 0) red[d >> 6] = v;
  __syncthreads();
  float var = (red[0] + red[1]) * (1.0f / 128.0f);
  float rinv = rsqrtf(var + 1e-6f) * scale;
  float xn = x * rinv * sc[d];
  __shared__ float sh[D];
  sh[d] = xn;
  __syncthreads();
  float rot = (d < 64) ? -sh[d + 64] : sh[d - 64];
  row[d] = f2bf(xn * cosp[s * D + d] + rot * sinp[s * D + d]);
}

// ---------------- flash attention v5: BARRIER-FREE, per-wave pipeline -------
// Each wave owns 16 q-rows + its PRIVATE double-buffered 32-key K tile in
// LDS, DMA'd by itself and synced with counted s_waitcnt vmcnt(8) (prefetch
// stays in flight across tiles; vmcnt(0) only on the last tile). ZERO
// __syncthreads -- the 4 waves free-run. V fragments direct from L2-resident
// Vt. Numerics identical to R4 (exp2 domain, hardened defer-rescale THR=8).
#define KVB 32   // keys per wave-tile
#define KP 128   // K LDS row pitch (u16), unpadded (DMA requirement)
#define PTP 72   // P pitch (u16): b64-write / b128-read aligned

__global__ __launch_bounds__(256) void k_flash(const u16* __restrict__ QKV,
                                               const u16* __restrict__ Vt,
                                               u16* __restrict__ O) {
  const int h = blockIdx.y, g = h >> 2;
  const int qt = (h < 8) ? (31 - (int)blockIdx.x) : (int)blockIdx.x;
  const int t = threadIdx.x;
  const int w = t >> 6, lane = t & 63, l15 = lane & 15, quad = lane >> 4;

  __shared__ __align__(16) u16 Klds[4][2][KVB * KP];  // per-wave double buffer
  __shared__ __align__(16) u16 Pt[4][16 * PTP];       // per-wave P staging

  u16* Kw[2] = {&Klds[w][0][0], &Klds[w][1][0]};

  const int qrow = qt * 64 + w * 16 + l15;

  short8 qf[4];
  {
    const u16* qp = QKV + (size_t)qrow * QKVP + h * D + quad * 8;
#pragma unroll
    for (int c = 0; c < 4; ++c) qf[c] = *(const short8*)(qp + c * 32);
  }

  float m = NEG_INF, l = 0.f;
  f32x4 oacc[8];
#pragma unroll
  for (int nc = 0; nc < 8; ++nc) oacc[nc] = (f32x4){0.f, 0.f, 0.f, 0.f};

  // per-wave tile count: covers keys 0 .. (max qrow of this wave)
  const int nt = ((qt * 64 + w * 16 + 15) >> 5) + 1;

  // wave-private K DMA: 8 x 16B per tile (4 rows per issue, 16 lanes/row)
  auto KLOAD = [&](int j0, u16* dst) {
#pragma unroll
    for (int it = 0; it < 8; ++it) {
      int rl = it * 4 + quad;                          // tile-local key row
      int gchunk = l15 ^ (rl & 7);                     // source swizzle
      const u16* gp = QKV + (size_t)(j0 + rl) * QKVP + 2048 + g * D + gchunk * 8;
      gload16(gp, dst + (it * 4) * KP);
    }
  };

  KLOAD(0, Kw[0]);
  for (int jt = 0; jt < nt; ++jt) {
    const u16* kb = Kw[jt & 1];
    if (jt + 1 < nt) {
      KLOAD((jt + 1) * KVB, Kw[(jt & 1) ^ 1]);
      asm volatile("s_waitcnt vmcnt(8)" ::: "memory");  // K(jt) landed; K(jt+1) in flight
    } else {
      asm volatile("s_waitcnt vmcnt(0)" ::: "memory");  // last tile: drain
    }

    const int j0 = jt * KVB;
    const u16* vbase = Vt + (size_t)g * D * S + j0;

    // V fragments (keys j0+quad*8..+7), L2-resident; latency hides under QK^T
    short8 vf[8];
#pragma unroll
    for (int nc = 0; nc < 8; ++nc)
      vf[nc] = *(const short8*)(vbase + (size_t)(nc * 16 + l15) * S + quad * 8);

    // ---- S^T = K x Q^T : row = key (quad*4+r +16sub), col = q-row (l15) ----
    f32x4 sa[2];
#pragma unroll
    for (int sub = 0; sub < 2; ++sub) {
      f32x4 acc = {0.f, 0.f, 0.f, 0.f};
#pragma unroll
      for (int c = 0; c < 4; ++c) {
        int ch = (c * 4 + quad) ^ (l15 & 7);  // undo source swizzle
        short8 kf = *(const short8*)&kb[(sub * 16 + l15) * KP + ch * 8];
        acc = __builtin_amdgcn_mfma_f32_16x16x32_bf16(kf, qf[c], acc, 0, 0, 0);
      }
      sa[sub] = acc;
    }

    if (jt == nt - 1) {  // causal mask: only the wave's last tile can cross
#pragma unroll
      for (int sub = 0; sub < 2; ++sub) {
        int keyb = j0 + sub * 16 + quad * 4;
#pragma unroll
        for (int r = 0; r < 4; ++r)
          if (keyb + r > qrow) sa[sub][r] = NEG_INF;
      }
    }

    // ---- online softmax (exp2 domain, hardened defer-rescale THR=8) -------
    float tmax = sa[0][0];
#pragma unroll
    for (int sub = 0; sub < 2; ++sub)
#pragma unroll
      for (int r = 0; r < 4; ++r) tmax = fmaxf(tmax, sa[sub][r]);
    tmax = fmaxf(tmax, __shfl_xor(tmax, 16, 64));
    tmax = fmaxf(tmax, __shfl_xor(tmax, 32, 64));
    if (jt == 0 || !__all(tmax - m <= 8.f)) {
      float mn = (jt == 0) ? tmax : fmaxf(m, tmax);
      float alpha = (jt == 0) ? 0.f : exp2_hw(m - mn);
      m = mn;
      l *= alpha;
#pragma unroll
      for (int nc = 0; nc < 8; ++nc) {
        oacc[nc][0] *= alpha; oacc[nc][1] *= alpha;
        oacc[nc][2] *= alpha; oacc[nc][3] *= alpha;
      }
    }
    float rs = 0.f;
#pragma unroll
    for (int sub = 0; sub < 2; ++sub) {
      float p0 = exp2_hw(sa[sub][0] - m);
      float p1 = exp2_hw(sa[sub][1] - m);
      float p2 = exp2_hw(sa[sub][2] - m);
      float p3 = exp2_hw(sa[sub][3] - m);
      rs += (p0 + p1) + (p2 + p3);
      u32 lo = cvt_pk_bf16(p0, p1);
      u32 hi = cvt_pk_bf16(p2, p3);
      *(uint2*)&Pt[w][l15 * PTP + sub * 16 + quad * 4] = make_uint2(lo, hi);
    }
    rs += __shfl_xor(rs, 16, 64);
    rs += __shfl_xor(rs, 32, 64);
    l += rs;

    // ---- O^T += V^T x P^T ----
    {
      short8 pf = *(const short8*)&Pt[w][l15 * PTP + quad * 8];
#pragma unroll
      for (int nc = 0; nc < 8; ++nc)
        oacc[nc] = __builtin_amdgcn_mfma_f32_16x16x32_bf16(vf[nc], pf, oacc[nc], 0, 0, 0);
    }
  }

  // ---- epilogue: O[q][d] = O^T / l ----
  float inv = 1.0f / l;
  u16* orow = O + (size_t)qrow * HID + h * D;
#pragma unroll
  for (int nc = 0; nc < 8; ++nc) {
    ushort4 wv;
    wv.x = f2bf(oacc[nc][0] * inv); wv.y = f2bf(oacc[nc][1] * inv);
    wv.z = f2bf(oacc[nc][2] * inv); wv.w = f2bf(oacc[nc][3] * inv);
    *(ushort4*)(orow + nc * 16 + quad * 4) = wv;
  }
}

// ---------------- final RMSNorm over HIDDEN=2048 ----------------------------
__device__ __forceinline__ float blockSum256(float v, float* red, int t) {
#pragma unroll
  for (int o = 32; o; o >>= 1) v += __shfl_xor(v, o, 64);
  if ((t & 63) == 0) red[t >> 6] = v;
  __syncthreads();
  v = red[0] + red[1] + red[2] + red[3];
  __syncthreads();
  return v;
}

__global__ __launch_bounds__(256) void k_fnorm(const float* __restrict__ X,
                                               const float* __restrict__ sc,
                                               float* __restrict__ out) {
  const int s = blockIdx.x, t = threadIdx.x;
  const float* row = X + (size_t)s * HID;
  float4 r0 = *(const float4*)(row + t * 8);
  float4 r1 = *(const float4*)(row + t * 8 + 4);
  float x[8] = {r0.x, r0.y, r0.z, r0.w, r1.x, r1.y, r1.z, r1.w};
  float ss = 0.f;
#pragma unroll
  for (int ii = 0; ii < 8; ++ii) ss += x[ii] * x[ii];
  __shared__ float red[4];
  float tot = blockSum256(ss, red, t);
  float rinv = rsqrtf(tot * (1.0f / 2048.0f) + 1e-6f);
  float4 s0 = *(const float4*)(sc + t * 8);
  float4 s1 = *(const float4*)(sc + t * 8 + 4);
  float4 w0 = make_float4(x[0] * rinv * s0.x, x[1] * rinv * s0.y,
                          x[2] * rinv * s0.z, x[3] * rinv * s0.w);
  float4 w1 = make_float4(x[4] * rinv * s1.x, x[5] * rinv * s1.y,
                          x[6] * rinv * s1.z, x[7] * rinv * s1.w);
  *(float4*)(out + (size_t)s * HID + t * 8) = w0;
  *(float4*)(out + (size_t)s * HID + t * 8 + 4) = w1;
}

extern "C" void kernel_launch(void* const* d_in, const int* in_sizes, int n_in,
                              void* d_out, int out_size, void* d_ws, size_t ws_size,
                              hipStream_t stream) {
  const float* hidden = (const float*)d_in[0];
  const float* cosp   = (const float*)d_in[1];
  const float* sinp   = (const float*)d_in[2];
  const float* Wq     = (const float*)d_in[3];
  const float* Wk     = (const float*)d_in[4];
  const float* Wv     = (const float*)d_in[5];
  const float* Wo     = (const float*)d_in[6];
  const float* qsc    = (const float*)d_in[7];
  const float* ksc    = (const float*)d_in[8];
  const float* lsc    = (const float*)d_in[9];
  float* out = (float*)d_out;

  char* ws = (char*)d_ws;
  u16*   Hb  = (u16*)(ws);                   // [S][HID] bf16, 8 MiB
  u16*   WoT = (u16*)(ws);                   // overlays Hb (after QKV GEMM)
  u16*   WT  = (u16*)(ws + (8ull << 20));    // [3072][2048] bf16, 12 MiB
  u16*   An  = (u16*)(ws + (8ull << 20));    // overlays WT (after QKV GEMM)
  u16*   QKV = (u16*)(ws + (20ull << 20));   // [S][3072] bf16, 12 MiB
  float* Ob  = (float*)(ws + (20ull << 20)); // overlays QKV (after flash)
  u16*   Vtb = (u16*)(ws + (32ull << 20));   // [512][2048] bf16, 2 MiB

  k_cvt<<<S * HID / (256 * 8), 256, 0, stream>>>(hidden, Hb);
  k_transpose_qkv<<<dim3(48, 32), 256, 0, stream>>>(Wq, Wk, Wv, WT);
  k_gemm_mfma<<<dim3(24, 16), 256, 0, stream>>>(Hb, WT, QKV, QKVP, 2048, 1);
  k_transpose<<<dim3(32, 32), 256, 0, stream>>>(Wo, WoT, 2048, 2048);  // Hb dead
  k_norm_rope<<<dim3(S, NH + NKV), 128, 0, stream>>>(QKV, qsc, ksc, cosp, sinp);
  k_vt<<<dim3(32, 8), 256, 0, stream>>>(QKV, Vtb);
  k_flash<<<dim3(32, NH), 256, 0, stream>>>(QKV, Vtb, An);
  k_gemm_mfma<<<dim3(16, 16), 256, 0, stream>>>(An, WoT, Ob, 2048, 2048, 0);
  k_fnorm<<<S, 256, 0, stream>>>(Ob, lsc, out);
}